// Round 1
// 701.675 us; speedup vs baseline: 1.0028x; 1.0028x over previous
//
#include <hip/hip_runtime.h>

#define NSAMP 2097152
#define DIM 64
#define NCLS 10
#define NT 5              // 5 column-tiles of 16: cols 0..63 = P, 64..79 = classes (padded)
#define TILES_PER_WAVE 8
#define WPB 4             // waves per block
#define SPB (WPB * 16 * TILES_PER_WAVE)  // 512 samples per block

typedef __attribute__((ext_vector_type(8))) short short8;
typedef __attribute__((ext_vector_type(4))) float floatx4;

// Precomputed operand matrices live in device globals (NOT d_ws):
//   g_mt_hi[80][64] bf16  (Mt[n][k]: n<64 -> P[k][n]; 64<=n<74 -> muP[n-64][k]; else 0)
//   g_mt_lo[80][64] bf16  (residual after hi)
//   g_b[0..15] = -0.5 mu_c P mu_c^T (or -1e30 pad), g_b[16] = alpha
__device__ short g_mt_hi[80 * 64];
__device__ short g_mt_lo[80 * 64];
__device__ float g_b[20];

// ---- bf16 helpers ---------------------------------------------------------
__device__ __forceinline__ unsigned bf16_rne_bits(float a) {
    unsigned u = __float_as_uint(a);
    return u + 0x7FFFu + ((u >> 16) & 1u);
}
__device__ __forceinline__ short f2bf(float a) { return (short)(bf16_rne_bits(a) >> 16); }
__device__ __forceinline__ float bf2f(short s) {
    return __uint_as_float(((unsigned)(unsigned short)s) << 16);
}
// pack two f32 -> two bf16 in one instruction (result lo = a, hi = b).
// Rounding mode of the cvt does not affect the hi/lo-split accuracy: the lo
// residual is computed against whatever hi the HW produced (exact fp32 sub).
__device__ __forceinline__ unsigned cvtpk_bf16(float a, float b) {
    unsigned r;
    asm("v_cvt_pk_bf16_f32 %0, %1, %2" : "=v"(r) : "v"(a), "v"(b));
    return r;
}

union S8 { unsigned u[4]; short8 v; };

// ---------------------------------------------------------------------------
__global__ __launch_bounds__(256) void precomp_kernel(
    const float* __restrict__ mu, const float* __restrict__ P,
    const float* __restrict__ alpha)
{
    __shared__ float muP_s[NCLS * DIM];
    __shared__ float b_s[NCLS];

    const int t = threadIdx.x;
    for (int idx = t; idx < NCLS * DIM; idx += 256) {
        const int c = idx >> 6, j = idx & 63;
        float s = 0.f;
        #pragma unroll
        for (int i = 0; i < DIM; ++i) s += mu[c * DIM + i] * P[i * DIM + j];
        muP_s[idx] = s;
    }
    __syncthreads();
    if (t < NCLS) {
        float q = 0.f;
        #pragma unroll
        for (int j = 0; j < DIM; ++j) q += muP_s[t * DIM + j] * mu[t * DIM + j];
        b_s[t] = -0.5f * q;
    }
    __syncthreads();
    for (int idx = t; idx < 80 * 64; idx += 256) {
        const int n = idx >> 6, k = idx & 63;
        float v = 0.f;
        if (n < 64)             v = P[k * DIM + n];
        else if (n < 64 + NCLS) v = muP_s[(n - 64) * DIM + k];
        const short hi = f2bf(v);
        g_mt_hi[idx] = hi;
        g_mt_lo[idx] = f2bf(v - bf2f(hi));
    }
    if (t < 16) g_b[t] = (t < NCLS) ? b_s[t] : -1e30f;
    if (t == 0) g_b[16] = alpha[0];
}

// ---------------------------------------------------------------------------
// Main kernel. One wave = one 16-sample M-tile per iteration, software-
// pipelined: tile it+1's global loads are issued before tile it's MFMAs.
//   G[16][80] = f_tile @ [P | muP^T]  via mfma_f32_16x16x32_bf16, hi/lo split
//   qf[m] = sum_j G[m][j] f[m][j]  (f re-read from LDS in C/D layout)
//   out[m] = alpha * (max_c(G[m][64+c] + b_c) - 0.5 qf[m])
// ---------------------------------------------------------------------------
__global__ __launch_bounds__(256) void mahal_kernel(
    const float* __restrict__ feat, float* __restrict__ out)
{
    const int tid  = threadIdx.x;
    const int w    = tid >> 6;
    const int lane = tid & 63;
    const int ln   = lane & 15;   // A: m-row / B: n-col / C: n-col
    const int q    = lane >> 4;   // k-group / C: m-group

    __shared__ float fl[WPB][16 * 68];   // stride 68 -> 2-way LDS aliasing (free)
    float* flw = &fl[w][0];

    // B fragments held in registers for the whole kernel (tile-invariant).
    short8 bh[NT][2], bl[NT][2];
    #pragma unroll
    for (int t = 0; t < NT; ++t)
        #pragma unroll
        for (int h = 0; h < 2; ++h) {
            const int off = (16 * t + ln) * 64 + h * 32 + q * 8;
            bh[t][h] = *(const short8*)(g_mt_hi + off);
            bl[t][h] = *(const short8*)(g_mt_lo + off);
        }
    const float bc    = g_b[ln];    // -1e30 for padded classes
    const float alpha = g_b[16];

    const long sbase0 = ((long)blockIdx.x * WPB + w) * (16 * TILES_PER_WAVE);
    const float* frbase = feat + (sbase0 + ln) * DIM + q * 8;

    // Prologue: load tile 0
    float4 t0 = *(const float4*)(frbase);
    float4 t1 = *(const float4*)(frbase + 4);
    float4 t2 = *(const float4*)(frbase + 32);
    float4 t3 = *(const float4*)(frbase + 36);

    #pragma unroll 1
    for (int it = 0; it < TILES_PER_WAVE; ++it) {
        // ---- prefetch tile it+1 FIRST: its latency hides under pack+MFMA+epilogue
        float4 n0 = {0,0,0,0}, n1 = {0,0,0,0}, n2 = {0,0,0,0}, n3 = {0,0,0,0};
        const bool more = (it + 1 < TILES_PER_WAVE);
        if (more) {
            const float* fr = frbase + (size_t)(it + 1) * (16 * DIM);
            n0 = *(const float4*)(fr);
            n1 = *(const float4*)(fr + 4);
            n2 = *(const float4*)(fr + 32);
            n3 = *(const float4*)(fr + 36);
        }

        // ---- stage current f to LDS for the epilogue (read back in C/D layout)
        float* fp = flw + ln * 68 + q * 8;
        *(float4*)(fp)      = t0;
        *(float4*)(fp + 4)  = t1;
        *(float4*)(fp + 32) = t2;
        *(float4*)(fp + 36) = t3;

        // ---- build hi/lo A fragments with v_cvt_pk_bf16_f32
        const float h0[8] = {t0.x, t0.y, t0.z, t0.w, t1.x, t1.y, t1.z, t1.w};
        const float h1[8] = {t2.x, t2.y, t2.z, t2.w, t3.x, t3.y, t3.z, t3.w};
        S8 ah0, ah1, al0, al1;
        #pragma unroll
        for (int i = 0; i < 4; ++i) {
            const float a0 = h0[2 * i], b0 = h0[2 * i + 1];
            const float a1 = h1[2 * i], b1 = h1[2 * i + 1];
            const unsigned rh0 = cvtpk_bf16(a0, b0);
            const unsigned rh1 = cvtpk_bf16(a1, b1);
            ah0.u[i] = rh0;
            ah1.u[i] = rh1;
            al0.u[i] = cvtpk_bf16(a0 - __uint_as_float(rh0 << 16),
                                  b0 - __uint_as_float(rh0 & 0xFFFF0000u));
            al1.u[i] = cvtpk_bf16(a1 - __uint_as_float(rh1 << 16),
                                  b1 - __uint_as_float(rh1 & 0xFFFF0000u));
        }
        const short8 A_h[2] = {ah0.v, ah1.v};
        const short8 A_l[2] = {al0.v, al1.v};

        // ---- MFMA: 5 n-tiles x 2 k-halves x 3 split terms
        floatx4 acc[NT];
        #pragma unroll
        for (int t = 0; t < NT; ++t) {
            floatx4 a = {0.f, 0.f, 0.f, 0.f};
            #pragma unroll
            for (int h = 0; h < 2; ++h) {
                a = __builtin_amdgcn_mfma_f32_16x16x32_bf16(A_h[h], bh[t][h], a, 0, 0, 0);
                a = __builtin_amdgcn_mfma_f32_16x16x32_bf16(A_h[h], bl[t][h], a, 0, 0, 0);
                a = __builtin_amdgcn_mfma_f32_16x16x32_bf16(A_l[h], bh[t][h], a, 0, 0, 0);
            }
            acc[t] = a;
        }

        // ---- epilogue: lane holds D[m = q*4+r][n = 16t+ln]
        float qf[4] = {0.f, 0.f, 0.f, 0.f};
        float sc[4];
        #pragma unroll
        for (int r = 0; r < 4; ++r) {
            const float* frow = flw + (q * 4 + r) * 68;
            #pragma unroll
            for (int t = 0; t < 4; ++t) qf[r] += acc[t][r] * frow[16 * t + ln];
            sc[r] = acc[4][r] + bc;
        }
        #pragma unroll
        for (int d = 1; d < 16; d <<= 1) {
            #pragma unroll
            for (int r = 0; r < 4; ++r) {
                qf[r] += __shfl_xor(qf[r], d);
                sc[r] = fmaxf(sc[r], __shfl_xor(sc[r], d));
            }
        }
        if (ln < 4) {
            const float qv = (ln == 0) ? qf[0] : (ln == 1) ? qf[1] : (ln == 2) ? qf[2] : qf[3];
            const float sv = (ln == 0) ? sc[0] : (ln == 1) ? sc[1] : (ln == 2) ? sc[2] : sc[3];
            out[sbase0 + (size_t)it * 16 + q * 4 + ln] = alpha * (sv - 0.5f * qv);
        }

        if (more) { t0 = n0; t1 = n1; t2 = n2; t3 = n3; }
    }
}

extern "C" void kernel_launch(void* const* d_in, const int* in_sizes, int n_in,
                              void* d_out, int out_size, void* d_ws, size_t ws_size,
                              hipStream_t stream) {
    const float* features = (const float*)d_in[0];
    const float* mu       = (const float*)d_in[1];
    const float* P        = (const float*)d_in[2];
    const float* alpha    = (const float*)d_in[3];
    (void)d_ws; (void)ws_size; (void)in_sizes; (void)n_in; (void)out_size;

    precomp_kernel<<<1, 256, 0, stream>>>(mu, P, alpha);
    mahal_kernel<<<NSAMP / SPB, 256, 0, stream>>>(features, (float*)d_out);
}